// Round 1
// baseline (313.566 us; speedup 1.0000x reference)
//
#include <hip/hip_runtime.h>
#include <hip/hip_bf16.h>
#include <math.h>

#define NV 131072
#define KOFF 27

typedef __attribute__((ext_vector_type(8))) short short8;
typedef __attribute__((ext_vector_type(4))) float floatx4;

__device__ inline float silu_f(float x) { return x / (1.0f + expf(-x)); }

// ---------- prep: W [k][cin][cout] f32 -> Wt [k][cout][cin] bf16; zero pad rows ----------
__global__ void prep_kernel(const float* __restrict__ W1, const float* __restrict__ W2,
                            __hip_bfloat16* __restrict__ W1t, __hip_bfloat16* __restrict__ W2t,
                            __hip_bfloat16* __restrict__ h0, __hip_bfloat16* __restrict__ h2) {
    int t = blockIdx.x * 256 + threadIdx.x;
    if (t < KOFF * 64 * 64) {
        int k = t >> 12, co = (t >> 6) & 63, ci = t & 63;
        int src = k * 4096 + ci * 64 + co;
        W1t[t] = __float2bfloat16(W1[src]);
        W2t[t] = __float2bfloat16(W2[src]);
    }
    if (t < 64) {  // padded zero row N for both staging buffers
        h0[NV * 64 + t] = __float2bfloat16(0.0f);
        h2[NV * 64 + t] = __float2bfloat16(0.0f);
    }
}

// ---------- FiLM: silu(emb) @ emb_W + emb_b -> ss [4,128] ----------
__global__ void film_kernel(const float* __restrict__ emb, const float* __restrict__ emb_W,
                            const float* __restrict__ emb_b, float* __restrict__ ss) {
    __shared__ float s_emb[4 * 512];
    int t = threadIdx.x;  // 512 threads
    for (int i = t; i < 2048; i += 512) s_emb[i] = silu_f(emb[i]);
    __syncthreads();
    int b = t >> 7, j = t & 127;
    float acc = emb_b[j];
    const float* eb = s_emb + b * 512;
    for (int e = 0; e < 512; ++e) acc += eb[e] * emb_W[e * 128 + j];
    ss[t] = acc;
}

// ---------- LN1 + silu -> h0 bf16 (one wave per row) ----------
__global__ void ln1_kernel(const float* __restrict__ feats, const float* __restrict__ gamma,
                           const float* __restrict__ beta, __hip_bfloat16* __restrict__ h0) {
    int row = blockIdx.x * 4 + (threadIdx.x >> 6);
    int c = threadIdx.x & 63;
    float x = feats[row * 64 + c];
    float s = x;
#pragma unroll
    for (int m = 1; m < 64; m <<= 1) s += __shfl_xor(s, m);
    float mu = s * (1.0f / 64.0f);
    float d = x - mu;
    float q = d * d;
#pragma unroll
    for (int m = 1; m < 64; m <<= 1) q += __shfl_xor(q, m);
    float inv = rsqrtf(q * (1.0f / 64.0f) + 1e-6f);
    float hn = d * inv * gamma[c] + beta[c];
    h0[row * 64 + c] = __float2bfloat16(silu_f(hn));
}

// ---------- gather-MFMA sparse conv over 27 offsets ----------
// EPI=0: conv1 -> +b1, LN2, FiLM, silu -> dst_bf (bf16)
// EPI=1: conv2 -> +b2 + feats -> dst_f32
template <int EPI>
__global__ __launch_bounds__(256) void conv_kernel(
    const __hip_bfloat16* __restrict__ hsrc,  // [NV+1, 64] bf16 (row NV = zeros)
    const __hip_bfloat16* __restrict__ Wt,    // [27, 64, 64] bf16, (k, cout, cin)
    const int* __restrict__ nbr,              // [NV, 27]
    const int* __restrict__ batch_idx,        // [NV]
    const float* __restrict__ ss,             // [4, 128] (scale | shift)
    const float* __restrict__ bias,           // [64]
    const float* __restrict__ feats,          // [NV, 64] (EPI=1)
    __hip_bfloat16* __restrict__ dst_bf,
    float* __restrict__ dst_f32) {
    __shared__ int s_idx[256 * KOFF];
    __shared__ float s_ss[512];

    int tid = threadIdx.x;
    int base = blockIdx.x * 256;  // 256 rows per block, 64 per wave
    for (int i = tid; i < 256 * KOFF; i += 256) s_idx[i] = nbr[base * KOFF + i];
    if (EPI == 0) {
        for (int i = tid; i < 512; i += 256) s_ss[i] = ss[i];
    }
    __syncthreads();

    int lane = tid & 63;
    int wave = tid >> 6;
    int l15 = lane & 15;
    int quad = lane >> 4;
    int wrow = wave * 64;  // this wave's first row within the block

    floatx4 acc[4][4];
#pragma unroll
    for (int m = 0; m < 4; ++m)
#pragma unroll
        for (int n = 0; n < 4; ++n) acc[m][n] = (floatx4){0.f, 0.f, 0.f, 0.f};

    const short8* hs8 = (const short8*)hsrc;  // 8 bf16 = 16B per element

#pragma unroll 1
    for (int k = 0; k < KOFF; ++k) {
        int jr[4];
#pragma unroll
        for (int m = 0; m < 4; ++m) jr[m] = s_idx[(wrow + m * 16 + l15) * KOFF + k];
        const short8* wk = (const short8*)(Wt + k * 4096);
#pragma unroll
        for (int ks = 0; ks < 2; ++ks) {
            int ko8 = ks * 4 + quad;  // (ks*32 + quad*8) / 8
            short8 bf[4];
#pragma unroll
            for (int n = 0; n < 4; ++n) bf[n] = wk[(n * 16 + l15) * 8 + ko8];
#pragma unroll
            for (int m = 0; m < 4; ++m) {
                short8 af = hs8[jr[m] * 8 + ko8];
#pragma unroll
                for (int n = 0; n < 4; ++n)
                    acc[m][n] = __builtin_amdgcn_mfma_f32_16x16x32_bf16(af, bf[n], acc[m][n], 0, 0, 0);
            }
        }
    }

    // epilogue: C/D layout col = lane&15, row = quad*4 + r
    float bias_v[4];
#pragma unroll
    for (int n = 0; n < 4; ++n) bias_v[n] = bias[n * 16 + l15];

#pragma unroll
    for (int m = 0; m < 4; ++m) {
#pragma unroll
        for (int r = 0; r < 4; ++r) {
            int row = base + wrow + m * 16 + quad * 4 + r;
            float v[4];
#pragma unroll
            for (int n = 0; n < 4; ++n) v[n] = acc[m][n][r] + bias_v[n];
            if (EPI == 0) {
                // LN (no affine) + FiLM + silu; row stats via quad-local butterfly
                float s = v[0] + v[1] + v[2] + v[3];
                float q = v[0] * v[0] + v[1] * v[1] + v[2] * v[2] + v[3] * v[3];
#pragma unroll
                for (int msk = 1; msk < 16; msk <<= 1) {
                    s += __shfl_xor(s, msk);
                    q += __shfl_xor(q, msk);
                }
                float mu = s * (1.0f / 64.0f);
                float var = q * (1.0f / 64.0f) - mu * mu;
                float inv = rsqrtf(var + 1e-6f);
                int b = batch_idx[row];
                const float* sb = s_ss + b * 128;
#pragma unroll
                for (int n = 0; n < 4; ++n) {
                    float hn = (v[n] - mu) * inv;
                    float x = hn * (1.0f + sb[n * 16 + l15]) + sb[64 + n * 16 + l15];
                    dst_bf[row * 64 + n * 16 + l15] = __float2bfloat16(silu_f(x));
                }
            } else {
#pragma unroll
                for (int n = 0; n < 4; ++n)
                    dst_f32[row * 64 + n * 16 + l15] = v[n] + feats[row * 64 + n * 16 + l15];
            }
        }
    }
}

extern "C" void kernel_launch(void* const* d_in, const int* in_sizes, int n_in,
                              void* d_out, int out_size, void* d_ws, size_t ws_size,
                              hipStream_t stream) {
    (void)in_sizes; (void)n_in; (void)out_size; (void)ws_size;
    const float* feats = (const float*)d_in[0];
    const float* emb   = (const float*)d_in[1];
    const float* gamma = (const float*)d_in[2];
    const float* beta  = (const float*)d_in[3];
    const float* W1    = (const float*)d_in[4];
    const float* b1    = (const float*)d_in[5];
    const float* W2    = (const float*)d_in[6];
    const float* b2    = (const float*)d_in[7];
    const float* emb_W = (const float*)d_in[8];
    const float* emb_b = (const float*)d_in[9];
    const int* nbr     = (const int*)d_in[10];
    const int* bidx    = (const int*)d_in[11];
    float* out = (float*)d_out;

    char* ws = (char*)d_ws;
    __hip_bfloat16* W1t = (__hip_bfloat16*)(ws);
    __hip_bfloat16* W2t = (__hip_bfloat16*)(ws + 221184);
    float* ss           = (float*)(ws + 442368);
    __hip_bfloat16* h0  = (__hip_bfloat16*)(ws + 444416);                 // [NV+1, 64]
    __hip_bfloat16* h2  = (__hip_bfloat16*)(ws + 444416 + 16777344);      // [NV+1, 64]

    prep_kernel<<<(KOFF * 64 * 64 + 255) / 256, 256, 0, stream>>>(W1, W2, W1t, W2t, h0, h2);
    film_kernel<<<1, 512, 0, stream>>>(emb, emb_W, emb_b, ss);
    ln1_kernel<<<NV / 4, 256, 0, stream>>>(feats, gamma, beta, h0);
    conv_kernel<0><<<NV / 256, 256, 0, stream>>>(h0, W1t, nbr, bidx, ss, b1, nullptr, h2, nullptr);
    conv_kernel<1><<<NV / 256, 256, 0, stream>>>(h2, W2t, nbr, bidx, ss, b2, feats, nullptr, out);
}